// Round 5
// baseline (268.950 us; speedup 1.0000x reference)
//
#include <hip/hip_runtime.h>
#include <hip/hip_bf16.h>

// ---------------------------------------------------------------------------
// EfficientViT block (LiteMLA + MBConv), B=16, C=256, H=W=32.
// Round 5: base = round-3 (known-good). Single change: gemm_bf stages B
// transposed in LDS (register repack, vector global loads, b128 stores) so
// BOTH operand frag reads are ds_read_b128. All global layouts c-major,
// identical to round 3.
// Workspace (byte offsets, liveness-aliased):
//   [0        , 25165824) qkvb           | h1b = [0, 33554432)   (K6+)
//   [25165824 , 33554432) xb             |
//   [33554432 , 58720256) dwb            | attnb = [33554432, 50331648) (K4b+)
//   [58720256 , 83886080) aggb           | h2b = [58720256, 92274688)  (K7+)
//   [83886080 , 88211456) kvp            |
//   [92274688 ,109051904) y1f (fp32)
//   [109051904,117440512) y1b
//   [117440512,119144448) wqb, wpb, w1b, w2b (bf16 weights)
// ---------------------------------------------------------------------------

typedef unsigned short u16;
typedef __attribute__((ext_vector_type(8))) short short8;
typedef __attribute__((ext_vector_type(4))) short short4v;
typedef __attribute__((ext_vector_type(4))) float f32x4;

#define HW 1024
#define EPSV 1e-5f
#define MFMA16(a, b, c) __builtin_amdgcn_mfma_f32_16x16x32_bf16((a), (b), (c), 0, 0, 0)
#define FB(n) ((((n) ^ ((n) >> 3))) & 7)   // B-row chunk swizzle

__device__ __forceinline__ u16 f2bf(float f) {
    union { __hip_bfloat16 h; u16 u; } c; c.h = __float2bfloat16(f); return c.u;
}
__device__ __forceinline__ float bf2f(u16 u) {
    union { u16 u; __hip_bfloat16 h; } c; c.u = u; return __bfloat162float(c.h);
}
__device__ __forceinline__ float hswish(float v) {
    return v * fminf(fmaxf(v + 3.f, 0.f), 6.f) * (1.f / 6.f);
}
__device__ __forceinline__ void gload_lds16(const u16* g, u16* lds) {
    __builtin_amdgcn_global_load_lds(
        (const __attribute__((address_space(1))) void*)g,
        (__attribute__((address_space(3))) void*)lds, 16, 0, 0);
}

// ---------------- P0: fp32 -> bf16 casts ------------------------------------
__global__ __launch_bounds__(256) void prep_k(
    const float* __restrict__ x,  u16* __restrict__ xb,
    const float* __restrict__ wq, u16* __restrict__ wqb,
    const float* __restrict__ wp, u16* __restrict__ wpb,
    const float* __restrict__ w1, u16* __restrict__ w1b,
    const float* __restrict__ w2, u16* __restrict__ w2b)
{
    const int N0 = 4194304, N1 = 196608, N2 = 131072, N3 = 262144;
    const int total = N0 + N1 + N2 + N3 + 262144;
    for (int i = blockIdx.x * 256 + threadIdx.x; i < total; i += gridDim.x * 256) {
        int id = i;
        if (id < N0) { xb[id]  = f2bf(x[id]);  continue; } id -= N0;
        if (id < N1) { wqb[id] = f2bf(wq[id]); continue; } id -= N1;
        if (id < N2) { wpb[id] = f2bf(wp[id]); continue; } id -= N2;
        if (id < N3) { w1b[id] = f2bf(w1[id]); continue; } id -= N3;
        w2b[id] = f2bf(w2[id]);
    }
}

// ---------------- bf16 MFMA GEMM: C[b][m][n] = sum_k A[m][k]*Act[b][k][n] ---
// Tile TM x 128, BK=64, NW=TM/32 waves (each wave 64m x 64n).
// As[m][64k]: chunk c in [0,8) stored at c ^ (m&7); staged via gload_lds16
// with the inverse swizzle on the GLOBAL source (rule 21) — unchanged.
// Bs[n][64k]: NEW — staged by register transpose: each thread loads 8 rows
// (k) x 4 cols (n) of the c-major global tile as short4v (coalesced), then
// stores 4 short8 chunks at Bs[n*64 + (( (k>>3) ^ FB(n) )*8)]. All vector
// subscripts compile-time (rule 20). Frag reads: ds_read_b128 both sides.
// EPI 0: bf16   1: +bias,hswish,bf16   2: BN+res -> f32+bf16   3: BN+res -> f32
template<int EPI, int TM>
__global__ __launch_bounds__(TM * 2) void gemm_bf(
    const u16* __restrict__ A, const u16* __restrict__ Bact,
    const float* __restrict__ s1, const float* __restrict__ s2,
    const float* __restrict__ Rres, float* __restrict__ outF,
    u16* __restrict__ outB, int M, int K)
{
    constexpr int NW = TM / 32;                 // waves per block
    constexpr int NT = TM * 2;                  // threads per block
    const int b  = blockIdx.z;
    const int n0 = blockIdx.x * 128;
    const int m0 = blockIdx.y * TM;
    const int t  = threadIdx.x;
    const int l  = t & 63, w = t >> 6;
    const int lr = t & 15, lg = (t >> 4) & 3;
    const int wm = (TM == 128) ? (w >> 1) : 0;
    const int wn = (TM == 128) ? (w & 1) : w;

    __shared__ __attribute__((aligned(16))) u16 As[TM * 64];
    __shared__ __attribute__((aligned(16))) u16 Bs[128 * 64];

    const u16* Ab0 = A + (size_t)m0 * K;
    const u16* Bp  = Bact + (size_t)b * K * HW + n0;

    // precompute per-thread B frag rows + swizzle
    int brow[4], bfb[4];
    #pragma unroll
    for (int j = 0; j < 4; ++j) {
        brow[j] = wn * 64 + j * 16 + lr;
        bfb[j]  = FB(brow[j]);
    }

    f32x4 zero4 = {0.f, 0.f, 0.f, 0.f};
    f32x4 acc[4][4];
    #pragma unroll
    for (int i = 0; i < 4; ++i)
        #pragma unroll
        for (int j = 0; j < 4; ++j) acc[i][j] = zero4;

    for (int k0 = 0; k0 < K; k0 += 64) {
        #pragma unroll
        for (int u = 0; u < 4; ++u) {            // stage A: TM*8 chunks
            int g = (u * NW + w) * 64 + l;
            int row = g >> 3, cl = g & 7;
            int cs = cl ^ (row & 7);
            gload_lds16(Ab0 + (size_t)row * K + k0 + cs * 8,
                        As + (size_t)(u * NW + w) * 512);
        }
        // stage B: register transpose. Work unit (kc in [0,8), n4 in [0,32)):
        // load B[kc*8+kk][n4*4..+4] (short4v) for kk=0..7, store 4 short8.
        #pragma unroll
        for (int q = 0; q < 256 / NT; ++q) {
            const int kc = (t >> 5) + q * (NT / 32);
            const int n4 = t & 31;
            short4v v[8];
            #pragma unroll
            for (int kk = 0; kk < 8; ++kk)
                v[kk] = *(const short4v*)(Bp + (size_t)(k0 + kc * 8 + kk) * HW + n4 * 4);
            #pragma unroll
            for (int nn = 0; nn < 4; ++nn) {
                const int n = n4 * 4 + nn;
                short8 wv = { v[0][nn], v[1][nn], v[2][nn], v[3][nn],
                              v[4][nn], v[5][nn], v[6][nn], v[7][nn] };
                *(short8*)(&Bs[n * 64 + ((kc ^ FB(n)) * 8)]) = wv;
            }
        }
        __syncthreads();
        #pragma unroll
        for (int kk = 0; kk < 2; ++kk) {
            short8 a[4], bb[4];
            #pragma unroll
            for (int i = 0; i < 4; ++i) {
                int row = wm * 64 + i * 16 + lr;
                a[i] = *(const short8*)(&As[row * 64 + (((kk * 4 + lg) ^ (lr & 7)) * 8)]);
            }
            #pragma unroll
            for (int j = 0; j < 4; ++j)
                bb[j] = *(const short8*)(&Bs[brow[j] * 64 + (((kk * 4 + lg) ^ bfb[j]) * 8)]);
            #pragma unroll
            for (int i = 0; i < 4; ++i)
                #pragma unroll
                for (int j = 0; j < 4; ++j)
                    acc[i][j] = MFMA16(a[i], bb[j], acc[i][j]);
        }
        __syncthreads();
    }

    const size_t obase = (size_t)b * M * HW;
    #pragma unroll
    for (int i = 0; i < 4; ++i) {
        #pragma unroll
        for (int r = 0; r < 4; ++r) {
            const int grow = m0 + wm * 64 + i * 16 + lg * 4 + r;
            float p1 = 0.f, p2 = 0.f;
            if (EPI == 1) { p1 = s1[grow]; }
            if (EPI >= 2) { p1 = s1[grow]; p2 = s2[grow]; }
            #pragma unroll
            for (int j = 0; j < 4; ++j) {
                const int gcol = n0 + wn * 64 + j * 16 + lr;
                const size_t off = obase + (size_t)grow * HW + gcol;
                float v = acc[i][j][r];
                if (EPI == 0) { outB[off] = f2bf(v); }
                if (EPI == 1) { v = hswish(v + p1); outB[off] = f2bf(v); }
                if (EPI == 2) { v = v * p1 + p2 + Rres[off]; outF[off] = v; outB[off] = f2bf(v); }
                if (EPI == 3) { v = v * p1 + p2 + Rres[off]; outF[off] = v; }
            }
        }
    }
}

// ---------------- depthwise conv (bf16 io, fp32 math) -----------------------
template<int KS, int PAD, int NCH, bool HS>
__global__ __launch_bounds__(256) void dwconv_k(
    const u16* __restrict__ in, const float* __restrict__ w,
    const float* __restrict__ bias, u16* __restrict__ out)
{
    constexpr int T = 32 + 2 * PAD;
    __shared__ float tile[T * T];
    const int plane = blockIdx.x;
    const int c = plane % NCH;
    const u16* ip = in + (size_t)plane * HW;
    const int t = threadIdx.x;
    for (int idx = t; idx < T * T; idx += 256) {
        int r = idx / T, cc = idx % T;
        int gr = r - PAD, gc = cc - PAD;
        float v = 0.f;
        if ((unsigned)gr < 32u && (unsigned)gc < 32u) v = bf2f(ip[gr * 32 + gc]);
        tile[idx] = v;
    }
    float wl[KS * KS];
    #pragma unroll
    for (int u = 0; u < KS * KS; ++u) wl[u] = w[c * KS * KS + u];
    const float bv = HS ? bias[c] : 0.f;
    __syncthreads();
    #pragma unroll
    for (int pj = 0; pj < 4; ++pj) {
        const int px = t + pj * 256;
        const int pr = px >> 5, pc = px & 31;
        float s = bv;
        #pragma unroll
        for (int dr = 0; dr < KS; ++dr)
            #pragma unroll
            for (int dc = 0; dc < KS; ++dc)
                s += tile[(pr + dr) * T + pc + dc] * wl[dr * KS + dc];
        if (HS) s = hswish(s);
        out[(size_t)plane * HW + px] = f2bf(s);
    }
}

// ---------------- grouped 1x1 (24 groups of 32->32), bf16 io ----------------
__global__ __launch_bounds__(256) void gconv_k(
    const u16* __restrict__ dw, const float* __restrict__ wpw,
    u16* __restrict__ agg)
{
    const int gx = blockIdx.x;               // g*4 + ntile
    const int g = gx >> 2, nt = gx & 3;
    const int b = blockIdx.y;
    const int n0 = nt * 256;
    const int t = threadIdx.x;
    __shared__ float dt[32][256];
    __shared__ float wl[32 * 32];
    const u16* dp = dw + ((size_t)b * 768 + g * 32) * HW + n0;
    for (int idx = t; idx < 32 * 256; idx += 256) {
        int i = idx >> 8, nn = idx & 255;
        dt[i][nn] = bf2f(dp[(size_t)i * HW + nn]);
    }
    for (int idx = t; idx < 1024; idx += 256) wl[idx] = wpw[g * 1024 + idx];
    __syncthreads();
    float acc[32] = {};
    #pragma unroll
    for (int i = 0; i < 32; ++i) {
        const float d = dt[i][t];
        #pragma unroll
        for (int oc = 0; oc < 32; ++oc) acc[oc] += wl[oc * 32 + i] * d;
    }
    u16* ap = agg + ((size_t)b * 768 + g * 32) * HW + n0;
    #pragma unroll
    for (int oc = 0; oc < 32; ++oc) ap[(size_t)oc * HW + t] = f2bf(acc[oc]);
}

// ---------------- K4a: kv partials via MFMA, zero LDS -----------------------
__global__ __launch_bounds__(64) void kv_k(
    const u16* __restrict__ qkvb, const u16* __restrict__ aggb,
    float* __restrict__ kvp)
{
    const int blk = blockIdx.x;              // bh*4 + nc
    const int bh = blk >> 2, nc = blk & 3;
    const int b = bh >> 4, h = bh & 15;
    const u16* src = (h < 8) ? qkvb + ((size_t)b * 768 + h * 96) * HW
                             : aggb + ((size_t)b * 768 + (h - 8) * 96) * HW;
    const u16* kp = src + 32 * HW + nc * 256;
    const u16* vp = src + 64 * HW + nc * 256;
    const int l = threadIdx.x;
    const int lr = l & 15, lg = l >> 4;

    f32x4 zero4 = {0.f, 0.f, 0.f, 0.f};
    f32x4 acc[2][3];
    #pragma unroll
    for (int i = 0; i < 2; ++i)
        #pragma unroll
        for (int j = 0; j < 3; ++j) acc[i][j] = zero4;

    short8 bones;
    #pragma unroll
    for (int g = 0; g < 8; ++g) bones[g] = (lr == 0) ? (short)0x3F80 : (short)0;

    for (int ks = 0; ks < 8; ++ks) {
        const int kn = ks * 32 + lg * 8;
        short8 a0 = *(const short8*)(kp + (size_t)lr * HW + kn);
        short8 a1 = *(const short8*)(kp + (size_t)(16 + lr) * HW + kn);
        #pragma unroll
        for (int g = 0; g < 8; ++g) {     // relu on bf16 bits
            if (((u16)a0[g]) & 0x8000) a0[g] = 0;
            if (((u16)a1[g]) & 0x8000) a1[g] = 0;
        }
        short8 b0 = *(const short8*)(vp + (size_t)lr * HW + kn);
        short8 b1 = *(const short8*)(vp + (size_t)(16 + lr) * HW + kn);
        acc[0][0] = MFMA16(a0, b0, acc[0][0]);
        acc[0][1] = MFMA16(a0, b1, acc[0][1]);
        acc[0][2] = MFMA16(a0, bones, acc[0][2]);
        acc[1][0] = MFMA16(a1, b0, acc[1][0]);
        acc[1][1] = MFMA16(a1, b1, acc[1][1]);
        acc[1][2] = MFMA16(a1, bones, acc[1][2]);
    }
    float* dst = kvp + (size_t)blk * 1056;
    #pragma unroll
    for (int dt = 0; dt < 2; ++dt)
        #pragma unroll
        for (int et = 0; et < 3; ++et)
            #pragma unroll
            for (int r = 0; r < 4; ++r) {
                const int d = dt * 16 + lg * 4 + r;
                const int e = et * 16 + lr;
                if (et < 2 || lr == 0) dst[d * 33 + e] = acc[dt][et][r];
            }
}

// ---------------- K4b: attn = normalize(relu(Q) @ kv) via MFMA --------------
__global__ __launch_bounds__(256) void attn_k(
    const u16* __restrict__ qkvb, const u16* __restrict__ aggb,
    const float* __restrict__ kvp, u16* __restrict__ attnb)
{
    const int blk = blockIdx.x;
    const int bh = blk >> 2, nc = blk & 3;
    const int b = bh >> 4, h = bh & 15;
    const u16* qp = (h < 8) ? qkvb + ((size_t)b * 768 + h * 96) * HW
                            : aggb + ((size_t)b * 768 + (h - 8) * 96) * HW;
    __shared__ u16 qs[256 * 40];
    const int t = threadIdx.x;
    #pragma unroll 4
    for (int u = 0; u < 32; ++u) {           // stage Q^T with relu
        int id = t + u * 256;                // 8192 elems
        int d = id >> 8, n = id & 255;
        u16 q = qp[(size_t)d * HW + nc * 256 + n];
        if (q & 0x8000) q = 0;
        qs[n * 40 + d] = q;
    }
    const int lr = t & 15, lg = (t >> 4) & 3, w = t >> 6;

    short8 bf[3];                            // kv as B-frags (sum 4 partials)
    const float* kb = kvp + (size_t)bh * 4 * 1056;
    #pragma unroll
    for (int et = 0; et < 3; ++et)
        #pragma unroll
        for (int j = 0; j < 8; ++j) {
            const int d = lg * 8 + j, e = et * 16 + lr;
            float s = 0.f;
            if (e <= 32) {
                #pragma unroll
                for (int c = 0; c < 4; ++c) s += kb[c * 1056 + d * 33 + e];
            }
            bf[et][j] = (short)f2bf(s);
        }
    __syncthreads();

    f32x4 zero4 = {0.f, 0.f, 0.f, 0.f};
    f32x4 acc[4][3];
    #pragma unroll
    for (int i = 0; i < 4; ++i) {
        const int row = w * 64 + i * 16 + lr;
        short8 a = *(const short8*)(&qs[row * 40 + lg * 8]);
        #pragma unroll
        for (int et = 0; et < 3; ++et) acc[i][et] = MFMA16(a, bf[et], zero4);
    }

    u16* ap = attnb + (size_t)b * 512 * HW + (size_t)h * 32 * HW;
    #pragma unroll
    for (int i = 0; i < 4; ++i) {
        float inv[4];
        #pragma unroll
        for (int r = 0; r < 4; ++r) {
            const float den = __shfl(acc[i][2][r], t & 48, 64);
            inv[r] = 1.f / (den + EPSV);
        }
        const int nbase = nc * 256 + w * 64 + i * 16 + lg * 4;
        #pragma unroll
        for (int et = 0; et < 2; ++et) {
            const int e = et * 16 + lr;
            short4v o;
            #pragma unroll
            for (int r = 0; r < 4; ++r) o[r] = (short)f2bf(acc[i][et][r] * inv[r]);
            *(short4v*)(ap + (size_t)e * HW + nbase) = o;
        }
    }
}

// ---------------------------------------------------------------------------
extern "C" void kernel_launch(void* const* d_in, const int* in_sizes, int n_in,
                              void* d_out, int out_size, void* d_ws, size_t ws_size,
                              hipStream_t stream)
{
    const float* x        = (const float*)d_in[0];
    const float* w_qkv    = (const float*)d_in[1];
    const float* w_agg_dw = (const float*)d_in[2];
    const float* w_agg_pw = (const float*)d_in[3];
    const float* w_proj   = (const float*)d_in[4];
    const float* bnp_s    = (const float*)d_in[5];
    const float* bnp_b    = (const float*)d_in[6];
    const float* w_mb1    = (const float*)d_in[7];
    const float* b_mb1    = (const float*)d_in[8];
    const float* w_mb_dw  = (const float*)d_in[9];
    const float* b_mb_dw  = (const float*)d_in[10];
    const float* w_mb2    = (const float*)d_in[11];
    const float* bn2_s    = (const float*)d_in[12];
    const float* bn2_b    = (const float*)d_in[13];
    float* out = (float*)d_out;
    char*  W   = (char*)d_ws;

    u16*   qkvb  = (u16*)(W + 0);
    u16*   xb    = (u16*)(W + 25165824);
    u16*   dwb   = (u16*)(W + 33554432);
    u16*   aggb  = (u16*)(W + 58720256);
    float* kvp   = (float*)(W + 83886080);
    u16*   attnb = (u16*)(W + 33554432);     // alias: dwb dead after gconv
    u16*   h1b   = (u16*)(W + 0);            // alias: qkvb+xb dead after attn
    u16*   h2b   = (u16*)(W + 58720256);     // alias: aggb+kvp dead after attn
    float* y1f   = (float*)(W + 92274688);
    u16*   y1b   = (u16*)(W + 109051904);
    u16*   wqb   = (u16*)(W + 117440512);
    u16*   wpb   = (u16*)(W + 117833728);
    u16*   w1b   = (u16*)(W + 118095872);
    u16*   w2b   = (u16*)(W + 118620160);

    prep_k<<<2048, 256, 0, stream>>>(x, xb, w_qkv, wqb, w_proj, wpb,
                                     w_mb1, w1b, w_mb2, w2b);
    gemm_bf<0, 128><<<dim3(8, 6, 16), 256, 0, stream>>>(
        wqb, xb, nullptr, nullptr, nullptr, nullptr, qkvb, 768, 256);
    dwconv_k<5, 2, 768, false><<<dim3(16 * 768), 256, 0, stream>>>(
        qkvb, w_agg_dw, nullptr, dwb);
    gconv_k<<<dim3(96, 16), 256, 0, stream>>>(dwb, w_agg_pw, aggb);
    kv_k<<<dim3(1024), 64, 0, stream>>>(qkvb, aggb, kvp);
    attn_k<<<dim3(1024), 256, 0, stream>>>(qkvb, aggb, kvp, attnb);
    gemm_bf<2, 64><<<dim3(8, 4, 16), 128, 0, stream>>>(
        wpb, attnb, bnp_s, bnp_b, x, y1f, y1b, 256, 512);
    gemm_bf<1, 128><<<dim3(8, 8, 16), 256, 0, stream>>>(
        w1b, y1b, b_mb1, nullptr, nullptr, nullptr, h1b, 1024, 256);
    dwconv_k<3, 1, 1024, true><<<dim3(16 * 1024), 256, 0, stream>>>(
        h1b, w_mb_dw, b_mb_dw, h2b);
    gemm_bf<3, 64><<<dim3(8, 4, 16), 128, 0, stream>>>(
        w2b, h2b, bn2_s, bn2_b, y1f, out, nullptr, 256, 1024);
}

// Round 6
// 266.274 us; speedup vs baseline: 1.0100x; 1.0100x over previous
//
#include <hip/hip_runtime.h>
#include <hip/hip_bf16.h>

// ---------------------------------------------------------------------------
// EfficientViT block (LiteMLA + MBConv), B=16, C=256, H=W=32.
// Round 6: base = round-5 (known-good). Single change: gemm_bf is now
// double-buffered 2-phase (T3 minimum recipe): issue next-tile staging
// BEFORE computing current tile; one vmcnt(0)+barrier per K-tile
// (__syncthreads). A via global_load_lds(16B); B via reg-transpose with
// T14 issue-early/write-late. All global layouts identical to round 5.
// Workspace (byte offsets, liveness-aliased):
//   [0        , 25165824) qkvb           | h1b = [0, 33554432)   (K6+)
//   [25165824 , 33554432) xb             |
//   [33554432 , 58720256) dwb            | attnb = [33554432, 50331648) (K4b+)
//   [58720256 , 83886080) aggb           | h2b = [58720256, 92274688)  (K7+)
//   [83886080 , 88211456) kvp            |
//   [92274688 ,109051904) y1f (fp32)
//   [109051904,117440512) y1b
//   [117440512,119144448) wqb, wpb, w1b, w2b (bf16 weights)
// ---------------------------------------------------------------------------

typedef unsigned short u16;
typedef __attribute__((ext_vector_type(8))) short short8;
typedef __attribute__((ext_vector_type(4))) short short4v;
typedef __attribute__((ext_vector_type(4))) float f32x4;

#define HW 1024
#define EPSV 1e-5f
#define MFMA16(a, b, c) __builtin_amdgcn_mfma_f32_16x16x32_bf16((a), (b), (c), 0, 0, 0)
#define FB(n) ((((n) ^ ((n) >> 3))) & 7)   // B-row chunk swizzle

__device__ __forceinline__ u16 f2bf(float f) {
    union { __hip_bfloat16 h; u16 u; } c; c.h = __float2bfloat16(f); return c.u;
}
__device__ __forceinline__ float bf2f(u16 u) {
    union { u16 u; __hip_bfloat16 h; } c; c.u = u; return __bfloat162float(c.h);
}
__device__ __forceinline__ float hswish(float v) {
    return v * fminf(fmaxf(v + 3.f, 0.f), 6.f) * (1.f / 6.f);
}
__device__ __forceinline__ void gload_lds16(const u16* g, u16* lds) {
    __builtin_amdgcn_global_load_lds(
        (const __attribute__((address_space(1))) void*)g,
        (__attribute__((address_space(3))) void*)lds, 16, 0, 0);
}

// ---------------- P0: fp32 -> bf16 casts ------------------------------------
__global__ __launch_bounds__(256) void prep_k(
    const float* __restrict__ x,  u16* __restrict__ xb,
    const float* __restrict__ wq, u16* __restrict__ wqb,
    const float* __restrict__ wp, u16* __restrict__ wpb,
    const float* __restrict__ w1, u16* __restrict__ w1b,
    const float* __restrict__ w2, u16* __restrict__ w2b)
{
    const int N0 = 4194304, N1 = 196608, N2 = 131072, N3 = 262144;
    const int total = N0 + N1 + N2 + N3 + 262144;
    for (int i = blockIdx.x * 256 + threadIdx.x; i < total; i += gridDim.x * 256) {
        int id = i;
        if (id < N0) { xb[id]  = f2bf(x[id]);  continue; } id -= N0;
        if (id < N1) { wqb[id] = f2bf(wq[id]); continue; } id -= N1;
        if (id < N2) { wpb[id] = f2bf(wp[id]); continue; } id -= N2;
        if (id < N3) { w1b[id] = f2bf(w1[id]); continue; } id -= N3;
        w2b[id] = f2bf(w2[id]);
    }
}

// ---------------- bf16 MFMA GEMM: C[b][m][n] = sum_k A[m][k]*Act[b][k][n] ---
// Tile TM x 128, BK=64, NW=TM/32 waves (each wave 64m x 64n), DOUBLE-buffered.
// Per K-tile: {issue A gload_lds(next) + B global->reg(next)} -> compute(cur)
// -> {ds_write B regs(next)} -> __syncthreads (vmcnt/lgkm drain overlapped
// with the compute phase). Swizzles identical to round 5.
// EPI 0: bf16   1: +bias,hswish,bf16   2: BN+res -> f32+bf16   3: BN+res -> f32
template<int EPI, int TM>
__global__ __launch_bounds__(TM * 2) void gemm_bf(
    const u16* __restrict__ A, const u16* __restrict__ Bact,
    const float* __restrict__ s1, const float* __restrict__ s2,
    const float* __restrict__ Rres, float* __restrict__ outF,
    u16* __restrict__ outB, int M, int K)
{
    constexpr int NW = TM / 32;                 // waves per block
    constexpr int NT = TM * 2;                  // threads per block
    constexpr int NQ = 256 / NT;                // B work units per thread
    constexpr int ABUF = TM * 64;
    constexpr int BBUF = 128 * 64;
    const int b  = blockIdx.z;
    const int n0 = blockIdx.x * 128;
    const int m0 = blockIdx.y * TM;
    const int t  = threadIdx.x;
    const int l  = t & 63, w = t >> 6;
    const int lr = t & 15, lg = (t >> 4) & 3;
    const int wm = (TM == 128) ? (w >> 1) : 0;
    const int wn = (TM == 128) ? (w & 1) : w;

    __shared__ __attribute__((aligned(16))) u16 As[2 * ABUF];
    __shared__ __attribute__((aligned(16))) u16 Bs[2 * BBUF];

    const u16* Ab0 = A + (size_t)m0 * K;
    const u16* Bp  = Bact + (size_t)b * K * HW + n0;

    // per-thread B frag rows + swizzle
    int brow[4], bfb[4];
    #pragma unroll
    for (int j = 0; j < 4; ++j) {
        brow[j] = wn * 64 + j * 16 + lr;
        bfb[j]  = FB(brow[j]);
    }

    short4v breg[NQ][8];                        // in-flight B tile (regs)

    auto issueA = [&](int k0, int sel) {
        u16* dst = As + (size_t)sel * ABUF;
        #pragma unroll
        for (int u = 0; u < 4; ++u) {           // TM*8 chunks / NT threads = 4
            int g = (u * NW + w) * 64 + l;
            int row = g >> 3, cl = g & 7;
            int cs = cl ^ (row & 7);
            gload_lds16(Ab0 + (size_t)row * K + k0 + cs * 8,
                        dst + (size_t)(u * NW + w) * 512);
        }
    };
    auto loadB = [&](int k0) {
        #pragma unroll
        for (int q = 0; q < NQ; ++q) {
            const int kc = (t >> 5) + q * (NT / 32);
            const int n4 = t & 31;
            #pragma unroll
            for (int kk = 0; kk < 8; ++kk)
                breg[q][kk] = *(const short4v*)(Bp + (size_t)(k0 + kc * 8 + kk) * HW + n4 * 4);
        }
    };
    auto writeB = [&](int sel) {
        u16* dst = Bs + (size_t)sel * BBUF;
        #pragma unroll
        for (int q = 0; q < NQ; ++q) {
            const int kc = (t >> 5) + q * (NT / 32);
            const int n4 = t & 31;
            #pragma unroll
            for (int nn = 0; nn < 4; ++nn) {
                const int n = n4 * 4 + nn;
                short8 wv = { breg[q][0][nn], breg[q][1][nn], breg[q][2][nn],
                              breg[q][3][nn], breg[q][4][nn], breg[q][5][nn],
                              breg[q][6][nn], breg[q][7][nn] };
                *(short8*)(&dst[n * 64 + ((kc ^ FB(n)) * 8)]) = wv;
            }
        }
    };

    f32x4 zero4 = {0.f, 0.f, 0.f, 0.f};
    f32x4 acc[4][4];
    #pragma unroll
    for (int i = 0; i < 4; ++i)
        #pragma unroll
        for (int j = 0; j < 4; ++j) acc[i][j] = zero4;

    const int ntk = K >> 6;
    // prologue: stage tile 0 into buffer 0
    issueA(0, 0);
    loadB(0);
    writeB(0);
    __syncthreads();

    int cur = 0;
    for (int tile = 0; tile < ntk; ++tile) {
        const int nxt = cur ^ 1;
        const bool pf = (tile + 1 < ntk);
        if (pf) { issueA((tile + 1) << 6, nxt); loadB((tile + 1) << 6); }

        const u16* Asb = As + (size_t)cur * ABUF;
        const u16* Bsb = Bs + (size_t)cur * BBUF;
        #pragma unroll
        for (int kk = 0; kk < 2; ++kk) {
            short8 a[4], bb[4];
            #pragma unroll
            for (int i = 0; i < 4; ++i) {
                int row = wm * 64 + i * 16 + lr;
                a[i] = *(const short8*)(&Asb[row * 64 + (((kk * 4 + lg) ^ (lr & 7)) * 8)]);
            }
            #pragma unroll
            for (int j = 0; j < 4; ++j)
                bb[j] = *(const short8*)(&Bsb[brow[j] * 64 + (((kk * 4 + lg) ^ bfb[j]) * 8)]);
            #pragma unroll
            for (int i = 0; i < 4; ++i)
                #pragma unroll
                for (int j = 0; j < 4; ++j)
                    acc[i][j] = MFMA16(a[i], bb[j], acc[i][j]);
        }
        if (pf) writeB(nxt);
        __syncthreads();
        cur = nxt;
    }

    const size_t obase = (size_t)b * M * HW;
    #pragma unroll
    for (int i = 0; i < 4; ++i) {
        #pragma unroll
        for (int r = 0; r < 4; ++r) {
            const int grow = m0 + wm * 64 + i * 16 + lg * 4 + r;
            float p1 = 0.f, p2 = 0.f;
            if (EPI == 1) { p1 = s1[grow]; }
            if (EPI >= 2) { p1 = s1[grow]; p2 = s2[grow]; }
            #pragma unroll
            for (int j = 0; j < 4; ++j) {
                const int gcol = n0 + wn * 64 + j * 16 + lr;
                const size_t off = obase + (size_t)grow * HW + gcol;
                float v = acc[i][j][r];
                if (EPI == 0) { outB[off] = f2bf(v); }
                if (EPI == 1) { v = hswish(v + p1); outB[off] = f2bf(v); }
                if (EPI == 2) { v = v * p1 + p2 + Rres[off]; outF[off] = v; outB[off] = f2bf(v); }
                if (EPI == 3) { v = v * p1 + p2 + Rres[off]; outF[off] = v; }
            }
        }
    }
}

// ---------------- depthwise conv (bf16 io, fp32 math) -----------------------
template<int KS, int PAD, int NCH, bool HS>
__global__ __launch_bounds__(256) void dwconv_k(
    const u16* __restrict__ in, const float* __restrict__ w,
    const float* __restrict__ bias, u16* __restrict__ out)
{
    constexpr int T = 32 + 2 * PAD;
    __shared__ float tile[T * T];
    const int plane = blockIdx.x;
    const int c = plane % NCH;
    const u16* ip = in + (size_t)plane * HW;
    const int t = threadIdx.x;
    for (int idx = t; idx < T * T; idx += 256) {
        int r = idx / T, cc = idx % T;
        int gr = r - PAD, gc = cc - PAD;
        float v = 0.f;
        if ((unsigned)gr < 32u && (unsigned)gc < 32u) v = bf2f(ip[gr * 32 + gc]);
        tile[idx] = v;
    }
    float wl[KS * KS];
    #pragma unroll
    for (int u = 0; u < KS * KS; ++u) wl[u] = w[c * KS * KS + u];
    const float bv = HS ? bias[c] : 0.f;
    __syncthreads();
    #pragma unroll
    for (int pj = 0; pj < 4; ++pj) {
        const int px = t + pj * 256;
        const int pr = px >> 5, pc = px & 31;
        float s = bv;
        #pragma unroll
        for (int dr = 0; dr < KS; ++dr)
            #pragma unroll
            for (int dc = 0; dc < KS; ++dc)
                s += tile[(pr + dr) * T + pc + dc] * wl[dr * KS + dc];
        if (HS) s = hswish(s);
        out[(size_t)plane * HW + px] = f2bf(s);
    }
}

// ---------------- grouped 1x1 (24 groups of 32->32), bf16 io ----------------
__global__ __launch_bounds__(256) void gconv_k(
    const u16* __restrict__ dw, const float* __restrict__ wpw,
    u16* __restrict__ agg)
{
    const int gx = blockIdx.x;               // g*4 + ntile
    const int g = gx >> 2, nt = gx & 3;
    const int b = blockIdx.y;
    const int n0 = nt * 256;
    const int t = threadIdx.x;
    __shared__ float dt[32][256];
    __shared__ float wl[32 * 32];
    const u16* dp = dw + ((size_t)b * 768 + g * 32) * HW + n0;
    for (int idx = t; idx < 32 * 256; idx += 256) {
        int i = idx >> 8, nn = idx & 255;
        dt[i][nn] = bf2f(dp[(size_t)i * HW + nn]);
    }
    for (int idx = t; idx < 1024; idx += 256) wl[idx] = wpw[g * 1024 + idx];
    __syncthreads();
    float acc[32] = {};
    #pragma unroll
    for (int i = 0; i < 32; ++i) {
        const float d = dt[i][t];
        #pragma unroll
        for (int oc = 0; oc < 32; ++oc) acc[oc] += wl[oc * 32 + i] * d;
    }
    u16* ap = agg + ((size_t)b * 768 + g * 32) * HW + n0;
    #pragma unroll
    for (int oc = 0; oc < 32; ++oc) ap[(size_t)oc * HW + t] = f2bf(acc[oc]);
}

// ---------------- K4a: kv partials via MFMA, zero LDS -----------------------
__global__ __launch_bounds__(64) void kv_k(
    const u16* __restrict__ qkvb, const u16* __restrict__ aggb,
    float* __restrict__ kvp)
{
    const int blk = blockIdx.x;              // bh*4 + nc
    const int bh = blk >> 2, nc = blk & 3;
    const int b = bh >> 4, h = bh & 15;
    const u16* src = (h < 8) ? qkvb + ((size_t)b * 768 + h * 96) * HW
                             : aggb + ((size_t)b * 768 + (h - 8) * 96) * HW;
    const u16* kp = src + 32 * HW + nc * 256;
    const u16* vp = src + 64 * HW + nc * 256;
    const int l = threadIdx.x;
    const int lr = l & 15, lg = l >> 4;

    f32x4 zero4 = {0.f, 0.f, 0.f, 0.f};
    f32x4 acc[2][3];
    #pragma unroll
    for (int i = 0; i < 2; ++i)
        #pragma unroll
        for (int j = 0; j < 3; ++j) acc[i][j] = zero4;

    short8 bones;
    #pragma unroll
    for (int g = 0; g < 8; ++g) bones[g] = (lr == 0) ? (short)0x3F80 : (short)0;

    for (int ks = 0; ks < 8; ++ks) {
        const int kn = ks * 32 + lg * 8;
        short8 a0 = *(const short8*)(kp + (size_t)lr * HW + kn);
        short8 a1 = *(const short8*)(kp + (size_t)(16 + lr) * HW + kn);
        #pragma unroll
        for (int g = 0; g < 8; ++g) {     // relu on bf16 bits
            if (((u16)a0[g]) & 0x8000) a0[g] = 0;
            if (((u16)a1[g]) & 0x8000) a1[g] = 0;
        }
        short8 b0 = *(const short8*)(vp + (size_t)lr * HW + kn);
        short8 b1 = *(const short8*)(vp + (size_t)(16 + lr) * HW + kn);
        acc[0][0] = MFMA16(a0, b0, acc[0][0]);
        acc[0][1] = MFMA16(a0, b1, acc[0][1]);
        acc[0][2] = MFMA16(a0, bones, acc[0][2]);
        acc[1][0] = MFMA16(a1, b0, acc[1][0]);
        acc[1][1] = MFMA16(a1, b1, acc[1][1]);
        acc[1][2] = MFMA16(a1, bones, acc[1][2]);
    }
    float* dst = kvp + (size_t)blk * 1056;
    #pragma unroll
    for (int dt = 0; dt < 2; ++dt)
        #pragma unroll
        for (int et = 0; et < 3; ++et)
            #pragma unroll
            for (int r = 0; r < 4; ++r) {
                const int d = dt * 16 + lg * 4 + r;
                const int e = et * 16 + lr;
                if (et < 2 || lr == 0) dst[d * 33 + e] = acc[dt][et][r];
            }
}

// ---------------- K4b: attn = normalize(relu(Q) @ kv) via MFMA --------------
__global__ __launch_bounds__(256) void attn_k(
    const u16* __restrict__ qkvb, const u16* __restrict__ aggb,
    const float* __restrict__ kvp, u16* __restrict__ attnb)
{
    const int blk = blockIdx.x;
    const int bh = blk >> 2, nc = blk & 3;
    const int b = bh >> 4, h = bh & 15;
    const u16* qp = (h < 8) ? qkvb + ((size_t)b * 768 + h * 96) * HW
                            : aggb + ((size_t)b * 768 + (h - 8) * 96) * HW;
    __shared__ u16 qs[256 * 40];
    const int t = threadIdx.x;
    #pragma unroll 4
    for (int u = 0; u < 32; ++u) {           // stage Q^T with relu
        int id = t + u * 256;                // 8192 elems
        int d = id >> 8, n = id & 255;
        u16 q = qp[(size_t)d * HW + nc * 256 + n];
        if (q & 0x8000) q = 0;
        qs[n * 40 + d] = q;
    }
    const int lr = t & 15, lg = (t >> 4) & 3, w = t >> 6;

    short8 bf[3];                            // kv as B-frags (sum 4 partials)
    const float* kb = kvp + (size_t)bh * 4 * 1056;
    #pragma unroll
    for (int et = 0; et < 3; ++et)
        #pragma unroll
        for (int j = 0; j < 8; ++j) {
            const int d = lg * 8 + j, e = et * 16 + lr;
            float s = 0.f;
            if (e <= 32) {
                #pragma unroll
                for (int c = 0; c < 4; ++c) s += kb[c * 1056 + d * 33 + e];
            }
            bf[et][j] = (short)f2bf(s);
        }
    __syncthreads();

    f32x4 zero4 = {0.f, 0.f, 0.f, 0.f};
    f32x4 acc[4][3];
    #pragma unroll
    for (int i = 0; i < 4; ++i) {
        const int row = w * 64 + i * 16 + lr;
        short8 a = *(const short8*)(&qs[row * 40 + lg * 8]);
        #pragma unroll
        for (int et = 0; et < 3; ++et) acc[i][et] = MFMA16(a, bf[et], zero4);
    }

    u16* ap = attnb + (size_t)b * 512 * HW + (size_t)h * 32 * HW;
    #pragma unroll
    for (int i = 0; i < 4; ++i) {
        float inv[4];
        #pragma unroll
        for (int r = 0; r < 4; ++r) {
            const float den = __shfl(acc[i][2][r], t & 48, 64);
            inv[r] = 1.f / (den + EPSV);
        }
        const int nbase = nc * 256 + w * 64 + i * 16 + lg * 4;
        #pragma unroll
        for (int et = 0; et < 2; ++et) {
            const int e = et * 16 + lr;
            short4v o;
            #pragma unroll
            for (int r = 0; r < 4; ++r) o[r] = (short)f2bf(acc[i][et][r] * inv[r]);
            *(short4v*)(ap + (size_t)e * HW + nbase) = o;
        }
    }
}

// ---------------------------------------------------------------------------
extern "C" void kernel_launch(void* const* d_in, const int* in_sizes, int n_in,
                              void* d_out, int out_size, void* d_ws, size_t ws_size,
                              hipStream_t stream)
{
    const float* x        = (const float*)d_in[0];
    const float* w_qkv    = (const float*)d_in[1];
    const float* w_agg_dw = (const float*)d_in[2];
    const float* w_agg_pw = (const float*)d_in[3];
    const float* w_proj   = (const float*)d_in[4];
    const float* bnp_s    = (const float*)d_in[5];
    const float* bnp_b    = (const float*)d_in[6];
    const float* w_mb1    = (const float*)d_in[7];
    const float* b_mb1    = (const float*)d_in[8];
    const float* w_mb_dw  = (const float*)d_in[9];
    const float* b_mb_dw  = (const float*)d_in[10];
    const float* w_mb2    = (const float*)d_in[11];
    const float* bn2_s    = (const float*)d_in[12];
    const float* bn2_b    = (const float*)d_in[13];
    float* out = (float*)d_out;
    char*  W   = (char*)d_ws;

    u16*   qkvb  = (u16*)(W + 0);
    u16*   xb    = (u16*)(W + 25165824);
    u16*   dwb   = (u16*)(W + 33554432);
    u16*   aggb  = (u16*)(W + 58720256);
    float* kvp   = (float*)(W + 83886080);
    u16*   attnb = (u16*)(W + 33554432);     // alias: dwb dead after gconv
    u16*   h1b   = (u16*)(W + 0);            // alias: qkvb+xb dead after attn
    u16*   h2b   = (u16*)(W + 58720256);     // alias: aggb+kvp dead after attn
    float* y1f   = (float*)(W + 92274688);
    u16*   y1b   = (u16*)(W + 109051904);
    u16*   wqb   = (u16*)(W + 117440512);
    u16*   wpb   = (u16*)(W + 117833728);
    u16*   w1b   = (u16*)(W + 118095872);
    u16*   w2b   = (u16*)(W + 118620160);

    prep_k<<<2048, 256, 0, stream>>>(x, xb, w_qkv, wqb, w_proj, wpb,
                                     w_mb1, w1b, w_mb2, w2b);
    gemm_bf<0, 128><<<dim3(8, 6, 16), 256, 0, stream>>>(
        wqb, xb, nullptr, nullptr, nullptr, nullptr, qkvb, 768, 256);
    dwconv_k<5, 2, 768, false><<<dim3(16 * 768), 256, 0, stream>>>(
        qkvb, w_agg_dw, nullptr, dwb);
    gconv_k<<<dim3(96, 16), 256, 0, stream>>>(dwb, w_agg_pw, aggb);
    kv_k<<<dim3(1024), 64, 0, stream>>>(qkvb, aggb, kvp);
    attn_k<<<dim3(1024), 256, 0, stream>>>(qkvb, aggb, kvp, attnb);
    gemm_bf<2, 64><<<dim3(8, 4, 16), 128, 0, stream>>>(
        wpb, attnb, bnp_s, bnp_b, x, y1f, y1b, 256, 512);
    gemm_bf<1, 128><<<dim3(8, 8, 16), 256, 0, stream>>>(
        w1b, y1b, b_mb1, nullptr, nullptr, nullptr, h1b, 1024, 256);
    dwconv_k<3, 1, 1024, true><<<dim3(16 * 1024), 256, 0, stream>>>(
        h1b, w_mb_dw, b_mb_dw, h2b);
    gemm_bf<3, 64><<<dim3(8, 4, 16), 128, 0, stream>>>(
        w2b, h2b, bn2_s, bn2_b, y1f, out, nullptr, 256, 1024);
}